// Round 14
// baseline (1024.804 us; speedup 1.0000x reference)
//
#include <hip/hip_runtime.h>

typedef unsigned short ushort_t;
typedef __bf16 bf16x8 __attribute__((ext_vector_type(8)));
typedef float f32x4 __attribute__((ext_vector_type(4)));
typedef unsigned short u16x8 __attribute__((ext_vector_type(8)));
typedef unsigned short u16x4 __attribute__((ext_vector_type(4)));

#define MFMA16(a, b, c) __builtin_amdgcn_mfma_f32_16x16x32_bf16(a, b, c, 0, 0, 0)

#define DIM 192
#define HEADS 6
#define GROUPS 8
#define CPG 24
#define HID 768
#define NWIN 4096
#define GN_N 1572864
#define SCALE 0.17677669529663687f

__device__ __forceinline__ ushort_t f2b(float f) {
  __bf16 h = (__bf16)f;
  return __builtin_bit_cast(unsigned short, h);
}
__device__ __forceinline__ float b2f(ushort_t u) {
  union { unsigned int u; float f; } v; v.u = ((unsigned int)u) << 16;
  return v.f;
}

// 8x8 transpose across lane-bits 3..5 vs register index (involution).
__device__ __forceinline__ void xpose8(ushort_t V[8], int C3) {
#pragma unroll
  for (int bb = 0; bb < 3; ++bb) {
    const int m = 1 << bb;
    int tt[8];
#pragma unroll
    for (int j = 0; j < 8; ++j) tt[j] = __shfl_xor((int)V[j], m << 3, 64);
#pragma unroll
    for (int j = 0; j < 8; ++j)
      if (((j >> bb) & 1) != ((C3 >> bb) & 1)) V[j] = (ushort_t)tt[j ^ m];
  }
}

// ---------------- weight transpose + bf16 convert: out[n][k] = in[k][n] ----
__global__ __launch_bounds__(256) void transpose_w(const float* __restrict__ in,
                                                   ushort_t* __restrict__ out,
                                                   int K, int N) {
  int id = blockIdx.x * 256 + threadIdx.x;
  if (id >= K * N) return;
  int n = id / K, k = id - n * K;
  out[id] = f2b(in[k * N + n]);
}

// ---------------- fold GroupNorm affine into weights, per batch ------------
// wdst[bb][n][k] = bf16(gw_bb[k] * wsrc[k][n]);  bdst[bb][n] = bsrc[n] + sum_k gb_bb[k]*wsrc[k][n]
// grid = 4 * (N/16); 256 threads: 16 cols x 16 k-quarters (12 k each)
__global__ __launch_bounds__(256) void fold_w(
    const float* __restrict__ wsrc, const float* __restrict__ bsrc,
    const float* __restrict__ stats,
    const float* __restrict__ nw, const float* __restrict__ nb,
    ushort_t* __restrict__ wdst, float* __restrict__ bdst, int N) {
  int nb16 = N >> 4;
  int blk = blockIdx.x;
  int bb = blk / nb16, ng = blk - bb * nb16;
  int tid = threadIdx.x;
  int colL = tid >> 4, kq = tid & 15;
  int col = ng * 16 + colL;
  ushort_t* wout = wdst + ((size_t)bb * N + col) * 192;
  float acc = 0.f;
#pragma unroll
  for (int j = 0; j < 12; ++j) {
    int k = kq * 12 + j;
    int g = k / 24;
    float mean = stats[(bb * 8 + g) * 2], rstd = stats[(bb * 8 + g) * 2 + 1];
    float gw = nw[k] * rstd;
    float gb = nb[k] - mean * gw;
    float w_ = wsrc[(size_t)k * N + col];
    wout[k] = f2b(gw * w_);
    acc += gb * w_;
  }
  for (int m = 1; m < 16; m <<= 1) acc += __shfl_xor(acc, m);
  if (kq == 0) bdst[bb * N + col] = bsrc[col] + acc;
}

// ---------------- GroupNorm stats for x (fp32), stage 1 --------------------
__global__ __launch_bounds__(256) void gn_stats1_f32(const float* __restrict__ x,
                                                     float* __restrict__ partial) {
  int bid = blockIdx.x;           // 32 * 64
  int sg = bid >> 6, chunk = bid & 63;
  const float* p = x + (size_t)sg * GN_N + (size_t)chunk * 24576;
  int tid = threadIdx.x;
  float s = 0.f, s2 = 0.f;
#pragma unroll
  for (int i = 0; i < 24; ++i) {
    float4 v = *(const float4*)(p + (size_t)(i * 256 + tid) * 4);
    s += v.x + v.y + v.z + v.w;
    s2 += v.x * v.x + v.y * v.y + v.z * v.z + v.w * v.w;
  }
  for (int m = 1; m < 64; m <<= 1) { s += __shfl_xor(s, m); s2 += __shfl_xor(s2, m); }
  __shared__ float red[8];
  int wv = tid >> 6;
  if ((tid & 63) == 0) { red[wv * 2] = s; red[wv * 2 + 1] = s2; }
  __syncthreads();
  if (tid == 0) {
    float a = 0.f, b = 0.f;
    for (int i = 0; i < 4; ++i) { a += red[i * 2]; b += red[i * 2 + 1]; }
    partial[bid * 2] = a; partial[bid * 2 + 1] = b;
  }
}

__global__ __launch_bounds__(64) void gn_stats2(const float* __restrict__ partial,
                                                float* __restrict__ stats) {
  int sg = blockIdx.x;
  int lane = threadIdx.x;
  float s = partial[(sg * 64 + lane) * 2];
  float s2 = partial[(sg * 64 + lane) * 2 + 1];
  for (int m = 1; m < 64; m <<= 1) { s += __shfl_xor(s, m); s2 += __shfl_xor(s2, m); }
  if (lane == 0) {
    const float invN = 1.0f / (float)GN_N;
    float mean = s * invN;
    float var = s2 * invN - mean * mean;
    stats[sg * 2] = mean;
    stats[sg * 2 + 1] = rsqrtf(var + 1e-5f);
  }
}

// ---------------- GN2 reduce: per-window partials -> stats -----------------
__global__ __launch_bounds__(64) void gn2_reduce(const float2* __restrict__ gpart,
                                                 float* __restrict__ stats) {
  int bid = blockIdx.x;            // b*8 + g
  int b = bid >> 3, g = bid & 7;
  int lane = threadIdx.x;
  float s = 0.f, s2 = 0.f;
  for (int w = lane; w < 1024; w += 64) {
    float2 v = gpart[((size_t)b * 1024 + w) * 8 + g];
    s += v.x; s2 += v.y;
  }
  for (int m = 1; m < 64; m <<= 1) { s += __shfl_xor(s, m); s2 += __shfl_xor(s2, m); }
  if (lane == 0) {
    const float invN = 1.0f / (float)GN_N;
    float mean = s * invN;
    float var = s2 * invN - mean * mean;
    stats[bid * 2] = mean;
    stats[bid * 2 + 1] = rsqrtf(var + 1e-5f);
  }
}

// ---------------- win_x: shift + windowize x -> buf (raw bf16) -------------
// GN1 is folded into the qkv weights, so this is a pure layout transform.
__global__ __launch_bounds__(256) void win_x(
    const float* __restrict__ x, ushort_t* __restrict__ buf) {
  int w = blockIdx.x;
  int b = w >> 10, wh = (w >> 5) & 31, ww = w & 31;
  int tid = threadIdx.x;
  int wave = tid >> 6, lane = tid & 63;
  int C3 = lane >> 3, I = lane & 7;

  __shared__ __align__(16) ushort_t tile[64][200];

  int px0 = (ww << 3) + 4;
  int px1 = (px0 + 4) & 255;

#pragma unroll
  for (int it = 0; it < 6; ++it) {
    int u = it * 256 + tid;
    int c = u >> 3, i = u & 7;
    int py = ((wh << 3) + i + 4) & 255;
    const float* src = x + (((size_t)(b * DIM + c)) << 16) + (py << 8);
    float4 ra = *(const float4*)(src + px0);
    float4 rb = *(const float4*)(src + px1);
    ushort_t V[8];
    V[0] = f2b(ra.x); V[1] = f2b(ra.y); V[2] = f2b(ra.z); V[3] = f2b(ra.w);
    V[4] = f2b(rb.x); V[5] = f2b(rb.y); V[6] = f2b(rb.z); V[7] = f2b(rb.w);
    xpose8(V, C3);   // V[j] = x(channel cbase+j, token I*8+C3)
    u16x8 wv;
#pragma unroll
    for (int j = 0; j < 8; ++j) wv[j] = V[j];
    int cbase = it * 32 + wave * 8;
    *(u16x8*)&tile[I * 8 + C3][cbase] = wv;
  }
  __syncthreads();

  ushort_t* bw = buf + (size_t)w * 12288;
#pragma unroll
  for (int it = 0; it < 6; ++it) {
    int u = it * 256 + tid;
    int token = u / 24, cv = u - token * 24;
    *(u16x8*)&bw[u * 8] = *(const u16x8*)&tile[token][cv * 8];
  }
}

// One qkv+attention pass for heads PH*2, PH*2+1.  PH literal (rule #20).
// Direct stores from named acc0..acc3 (keeps VGPR <= 64: 2 blocks/CU).
#define QKV_ATTN_PASS(PH)                                                      \
  {                                                                            \
    {                                                                          \
      int sec = wave >> 2;              /* 0=q 1=k 2=v */                      \
      int tloc = wave & 3;                                                     \
      int cols16 = sec * 192 + (PH) * 64 + tloc * 16;                          \
      int lh = tloc >> 1;                                                      \
      int d = ((tloc & 1) << 4) + p;                                           \
      f32x4 acc0 = zz, acc1 = zz, acc2 = zz, acc3 = zz;                        \
      _Pragma("unroll")                                                        \
      for (int ks = 0; ks < 6; ++ks) {                                         \
        int k0 = ks * 32 + q8 * 8;                                             \
        bf16x8 bfr = *(const bf16x8*)(qkvT + (size_t)(cols16 + p) * DIM + k0); \
        acc0 = MFMA16(*(const bf16x8*)&tile[0 * 16 + p][k0], bfr, acc0);       \
        acc1 = MFMA16(*(const bf16x8*)&tile[1 * 16 + p][k0], bfr, acc1);       \
        acc2 = MFMA16(*(const bf16x8*)&tile[2 * 16 + p][k0], bfr, acc2);       \
        acc3 = MFMA16(*(const bf16x8*)&tile[3 * 16 + p][k0], bfr, acc3);       \
      }                                                                        \
      float bias = qkv_b[cols16 + p];                                          \
      if (sec == 0) {                                                          \
        int base = q8 * 4;                                                     \
        _Pragma("unroll")                                                      \
        for (int r = 0; r < 4; ++r) {                                          \
          qkP[lh][(0 * 16 + base + r) * 40 + d] = f2b((acc0[r] + bias) * SCALE); \
          qkP[lh][(1 * 16 + base + r) * 40 + d] = f2b((acc1[r] + bias) * SCALE); \
          qkP[lh][(2 * 16 + base + r) * 40 + d] = f2b((acc2[r] + bias) * SCALE); \
          qkP[lh][(3 * 16 + base + r) * 40 + d] = f2b((acc3[r] + bias) * SCALE); \
        }                                                                      \
      } else if (sec == 1) {                                                   \
        int base = q8 * 4;                                                     \
        _Pragma("unroll")                                                      \
        for (int r = 0; r < 4; ++r) {                                          \
          qkP[lh][2560 + (0 * 16 + base + r) * 40 + d] = f2b(acc0[r] + bias);  \
          qkP[lh][2560 + (1 * 16 + base + r) * 40 + d] = f2b(acc1[r] + bias);  \
          qkP[lh][2560 + (2 * 16 + base + r) * 40 + d] = f2b(acc2[r] + bias);  \
          qkP[lh][2560 + (3 * 16 + base + r) * 40 + d] = f2b(acc3[r] + bias);  \
        }                                                                      \
      } else {                                                                 \
        u16x4 v0, v1, v2, v3;                                                  \
        _Pragma("unroll")                                                      \
        for (int r = 0; r < 4; ++r) {                                          \
          v0[r] = f2b(acc0[r] + bias);                                         \
          v1[r] = f2b(acc1[r] + bias);                                         \
          v2[r] = f2b(acc2[r] + bias);                                         \
          v3[r] = f2b(acc3[r] + bias);                                         \
        }                                                                      \
        int base = d * 72 + q8 * 4;                                            \
        *(u16x4*)&vT[lh][base + 0]  = v0;                                      \
        *(u16x4*)&vT[lh][base + 16] = v1;                                      \
        *(u16x4*)&vT[lh][base + 32] = v2;                                      \
        *(u16x4*)&vT[lh][base + 48] = v3;                                      \
      }                                                                        \
    }                                                                          \
    __syncthreads(); /* B2 */                                                  \
    {                                                                          \
      int lh = (wave >> 2) & 1, quad = wave & 3;                               \
      int rb_ = quad << 4;                                                     \
      int k0 = q8 * 8;                                                         \
      f32x4 s0 = zz, s1 = zz, s2 = zz, s3 = zz;                                \
      if (wave < 8) {                                                          \
        const ushort_t* qh = &qkP[lh][0];                                      \
        const ushort_t* kh = &qkP[lh][2560];                                   \
        bf16x8 aq = *(const bf16x8*)&qh[(rb_ + p) * 40 + k0];                  \
        bf16x8 bk0 = *(const bf16x8*)&kh[(0 + p) * 40 + k0];                   \
        bf16x8 bk1 = *(const bf16x8*)&kh[(16 + p) * 40 + k0];                  \
        bf16x8 bk2 = *(const bf16x8*)&kh[(32 + p) * 40 + k0];                  \
        bf16x8 bk3 = *(const bf16x8*)&kh[(48 + p) * 40 + k0];                  \
        s0 = MFMA16(aq, bk0, zz);                                              \
        s1 = MFMA16(aq, bk1, zz);                                              \
        s2 = MFMA16(aq, bk2, zz);                                              \
        s3 = MFMA16(aq, bk3, zz);                                              \
      }                                                                        \
      __syncthreads(); /* B3: q/k reads done before P overwrite */             \
      if (wave < 8) {                                                          \
        ushort_t* Ph = &qkP[lh][0];                                            \
        _Pragma("unroll")                                                      \
        for (int r = 0; r < 4; ++r) {                                          \
          float m = fmaxf(fmaxf(s0[r], s1[r]), fmaxf(s2[r], s3[r]));           \
          for (int msk = 1; msk < 16; msk <<= 1) m = fmaxf(m, __shfl_xor(m, msk)); \
          float e0 = __expf(s0[r] - m);                                        \
          float e1 = __expf(s1[r] - m);                                        \
          float e2 = __expf(s2[r] - m);                                        \
          float e3 = __expf(s3[r] - m);                                        \
          float sum = e0 + e1 + e2 + e3;                                       \
          for (int msk = 1; msk < 16; msk <<= 1) sum += __shfl_xor(sum, msk);  \
          float inv = 1.0f / sum;                                              \
          int row = rb_ + q8 * 4 + r;                                          \
          Ph[row * 72 + 0 + p]  = f2b(e0 * inv);                               \
          Ph[row * 72 + 16 + p] = f2b(e1 * inv);                               \
          Ph[row * 72 + 32 + p] = f2b(e2 * inv);                               \
          Ph[row * 72 + 48 + p] = f2b(e3 * inv);                               \
        }                                                                      \
        f32x4 o0 = zz, o1 = zz;                                                \
        _Pragma("unroll")                                                      \
        for (int ks = 0; ks < 2; ++ks) {                                       \
          int kk = ks * 32 + k0;                                               \
          bf16x8 bv0 = *(const bf16x8*)&vT[lh][(0 + p) * 72 + kk];             \
          bf16x8 bv1 = *(const bf16x8*)&vT[lh][(16 + p) * 72 + kk];            \
          bf16x8 ap = *(const bf16x8*)&Ph[(rb_ + p) * 72 + kk];                \
          o0 = MFMA16(ap, bv0, o0);                                            \
          o1 = MFMA16(ap, bv1, o1);                                            \
        }                                                                      \
        size_t ob = (size_t)w * 12288 + (size_t)(rb_ + q8 * 4) * 192 +         \
                    ((PH) * 2 + lh) * 32 + p;                                  \
        _Pragma("unroll")                                                      \
        for (int r = 0; r < 4; ++r) {                                          \
          obuf[ob + (size_t)r * 192]      = f2b(o0[r]);                        \
          obuf[ob + (size_t)r * 192 + 16] = f2b(o1[r]);                        \
        }                                                                      \
      }                                                                        \
    }                                                                          \
  }

// ---------------- K_a: qkv + attention (raw-x win in; O in place) ----------
__global__ __launch_bounds__(768, 3) void attn_kernel(
    const ushort_t* __restrict__ buf_xn,
    const ushort_t* __restrict__ qkvTb_, const float* __restrict__ qkvbb_,
    ushort_t* __restrict__ obuf) {
  int w = blockIdx.x;
  int tid = threadIdx.x;
  int wave = tid >> 6, lane = tid & 63;
  int p = lane & 15, q8 = lane >> 4;

  const ushort_t* qkvT = qkvTb_ + (size_t)(w >> 10) * 110592;   // 576*192
  const float* qkv_b = qkvbb_ + (w >> 10) * 576;

  __shared__ __align__(16) ushort_t tile[64][200];  // x win (token-major)
  __shared__ __align__(16) ushort_t qkP[2][5120];   // q|k -> P, per head
  __shared__ __align__(16) ushort_t vT[2][2304];    // v^T [32][72]

  // ---- phase 0: coalesced copy buf -> tile ----
  const ushort_t* bw = buf_xn + (size_t)w * 12288;
#pragma unroll
  for (int it = 0; it < 2; ++it) {
    int u = it * 768 + tid;
    int token = u / 24, cv = u - token * 24;
    *(u16x8*)&tile[token][cv * 8] = *(const u16x8*)&bw[u * 8];
  }
  __syncthreads();   // B1

  const f32x4 zz = {0.f, 0.f, 0.f, 0.f};

  QKV_ATTN_PASS(0)
  __syncthreads();   // B4
  QKV_ATTN_PASS(1)
  __syncthreads();   // B4
  QKV_ATTN_PASS(2)
}

// ---------------- K_b: proj GEMM + residual-1 -> x_mid (in place) ----------
__global__ __launch_bounds__(256) void proj_kernel(
    ushort_t* __restrict__ buf,           // in: O, out: x_mid (windowed)
    const ushort_t* __restrict__ projT, const float* __restrict__ proj_b,
    const float* __restrict__ x, float2* __restrict__ gpart) {
  int w = blockIdx.x;
  int b = w >> 10, wh = (w >> 5) & 31, ww = w & 31;
  int tid = threadIdx.x;
  int wave = tid >> 6, lane = tid & 63;
  int p = lane & 15, q8 = lane >> 4;
  int C3 = lane >> 3, I = lane & 7;

  __shared__ __align__(16) ushort_t otile[64][200];  // O -> proj-out -> resid
  __shared__ __align__(16) float2 red[1536];

  ushort_t* bw = buf + (size_t)w * 12288;

#pragma unroll
  for (int it = 0; it < 6; ++it) {
    int idx = (it * 256 + tid) * 8;
    int t = idx / 192, c = idx - t * 192;
    *(u16x8*)&otile[t][c] = *(const u16x8*)&bw[idx];
  }
  __syncthreads();

  const f32x4 zz = {0.f, 0.f, 0.f, 0.f};
  f32x4 prr[3][4];
#pragma unroll
  for (int rd = 0; rd < 3; ++rd) {
    int col = rd * 64 + wave * 16 + p;
#pragma unroll
    for (int mt = 0; mt < 4; ++mt) prr[rd][mt] = zz;
#pragma unroll
    for (int ks = 0; ks < 6; ++ks) {
      int k0 = ks * 32 + q8 * 8;
      bf16x8 bfr = *(const bf16x8*)(projT + (size_t)col * DIM + k0);
      prr[rd][0] = MFMA16(*(const bf16x8*)&otile[0 * 16 + p][k0], bfr, prr[rd][0]);
      prr[rd][1] = MFMA16(*(const bf16x8*)&otile[1 * 16 + p][k0], bfr, prr[rd][1]);
      prr[rd][2] = MFMA16(*(const bf16x8*)&otile[2 * 16 + p][k0], bfr, prr[rd][2]);
      prr[rd][3] = MFMA16(*(const bf16x8*)&otile[3 * 16 + p][k0], bfr, prr[rd][3]);
    }
  }
  __syncthreads();

#pragma unroll
  for (int rd = 0; rd < 3; ++rd) {
    int col = rd * 64 + wave * 16 + p;
    float bias = proj_b[col];
#pragma unroll
    for (int mt = 0; mt < 4; ++mt)
#pragma unroll
      for (int r = 0; r < 4; ++r)
        otile[mt * 16 + q8 * 4 + r][col] = f2b(prr[rd][mt][r] + bias);
  }
  __syncthreads();

  int px0 = (ww << 3) + 4;
  int px1 = (px0 + 4) & 255;

#pragma unroll
  for (int it = 0; it < 6; ++it) {
    int u = it * 256 + tid;
    int c = u >> 3, i = u & 7;
    int cbase = it * 32 + wave * 8;
    u16x8 rr = *(const u16x8*)&otile[I * 8 + C3][cbase];
    ushort_t V[8];
#pragma unroll
    for (int j = 0; j < 8; ++j) V[j] = rr[j];
    xpose8(V, C3);
    int py = ((wh << 3) + i + 4) & 255;
    const float* src = x + (((size_t)(b * DIM + c)) << 16) + (py << 8);
    float4 ra = *(const float4*)(src + px0);
    V[0] = f2b(ra.x + b2f(V[0]));
    V[1] = f2b(ra.y + b2f(V[1]));
    V[2] = f2b(ra.z + b2f(V[2]));
    V[3] = f2b(ra.w + b2f(V[3]));
    float4 rb2 = *(const float4*)(src + px1);
    V[4] = f2b(rb2.x + b2f(V[4]));
    V[5] = f2b(rb2.y + b2f(V[5]));
    V[6] = f2b(rb2.z + b2f(V[6]));
    V[7] = f2b(rb2.w + b2f(V[7]));
    xpose8(V, C3);
    u16x8 wv;
#pragma unroll
    for (int j = 0; j < 8; ++j) wv[j] = V[j];
    *(u16x8*)&otile[I * 8 + C3][cbase] = wv;
  }
  __syncthreads();

#pragma unroll
  for (int it = 0; it < 6; ++it) {
    int u = it * 256 + tid;
    int token = u / 24, cv = u - token * 24;
    u16x8 v = *(const u16x8*)&otile[token][cv * 8];
    *(u16x8*)&bw[u * 8] = v;
    float s_ = 0.f, s2_ = 0.f;
#pragma unroll
    for (int t = 0; t < 8; ++t) { float f = b2f(v[t]); s_ += f; s2_ += f * f; }
    red[u] = make_float2(s_, s2_);
  }
  __syncthreads();

  for (int g = wave; g < 8; g += 4) {
    float s_ = 0.f, s2_ = 0.f;
#pragma unroll
    for (int j = 0; j < 3; ++j) {
      float2 t_ = red[lane * 24 + g * 3 + j];
      s_ += t_.x; s2_ += t_.y;
    }
    for (int m = 1; m < 64; m <<= 1) { s_ += __shfl_xor(s_, m); s2_ += __shfl_xor(s2_, m); }
    if (lane == 0) gpart[(size_t)w * 8 + g] = make_float2(s_, s2_);
  }
}

// ---------------- fused MLP + residual2 (GN2 folded into W1') --------------
// fill = pure coalesced copy; no tables; LDS 34816 -> 4 blocks/CU.
__global__ __launch_bounds__(256, 4) void mlp_kernel(
    const ushort_t* __restrict__ x_mid,
    const ushort_t* __restrict__ w1b, const float* __restrict__ b1b,
    const ushort_t* __restrict__ w2T, const float* __restrict__ b2,
    float* __restrict__ out) {
  int bid = blockIdx.x;
  int b = bid >> 10, y = (bid >> 2) & 255, xq = bid & 3;
  int x0 = xq * 64;
  int tid = threadIdx.x;
  int wave = tid >> 6, lane = tid & 63;
  int p = lane & 15, q = lane >> 4;

  __shared__ ushort_t xn[64][200];   // xm tile, later mlp-out staging
  __shared__ ushort_t hb[64][72];    // hidden chunk [token][hid]

  const ushort_t* w1T = w1b + (size_t)b * 147456;   // 768*192
  const float* b1 = b1b + b * 768;

  int yp = (y + 252) & 255;          // (y - 4) mod 256
  int whp = yp >> 3, ip = yp & 7;
  size_t winrow = ((size_t)b * 1024 + (size_t)whp * 32) * 12288;

  // pure-copy fill (GN2 folded into weights)
  for (int u = tid; u < 1536; u += 256) {
    int tx = u / 24, ch = u - tx * 24;
    int c8 = ch * 8;
    int xp = (x0 + tx + 252) & 255;  // (x - 4) mod 256
    *(u16x8*)&xn[tx][c8] =
        *(const u16x8*)(x_mid + winrow + (size_t)(xp >> 3) * 12288 +
                        (size_t)(ip * 8 + (xp & 7)) * 192 + c8);
  }
  __syncthreads();

  const f32x4 zz = {0.f, 0.f, 0.f, 0.f};
  f32x4 accO[4][3];
#pragma unroll
  for (int mt = 0; mt < 4; ++mt)
#pragma unroll
    for (int nt = 0; nt < 3; ++nt) accO[mt][nt] = zz;

  for (int ch = 0; ch < 12; ++ch) {
    int hcol16 = ch * 64 + wave * 16;
    f32x4 a1[4];
#pragma unroll
    for (int mt = 0; mt < 4; ++mt) a1[mt] = zz;
#pragma unroll
    for (int ks = 0; ks < 6; ++ks) {
      int k0 = ks * 32 + q * 8;
      bf16x8 wfr = *(const bf16x8*)(w1T + (size_t)(hcol16 + p) * DIM + k0);
#pragma unroll
      for (int mt = 0; mt < 4; ++mt) {
        bf16x8 afr = *(const bf16x8*)&xn[mt * 16 + p][k0];
        a1[mt] = MFMA16(wfr, afr, a1[mt]);   // swapped: weights=rows, tokens=cols
      }
    }
    float4 bb = *(const float4*)&b1[hcol16 + q * 4];
    if (ch) __syncthreads();
#pragma unroll
    for (int mt = 0; mt < 4; ++mt) {
      u16x4 hv;
#pragma unroll
      for (int r = 0; r < 4; ++r) {
        float vv = a1[mt][r] + ((const float*)&bb)[r];
        float g = vv / (1.0f + __expf(-1.702f * vv));   // sigmoid-GELU
        hv[r] = f2b(g);
      }
      *(u16x4*)&hb[mt * 16 + p][wave * 16 + q * 4] = hv;
    }
    __syncthreads();
#pragma unroll
    for (int ks = 0; ks < 2; ++ks) {
      int k0 = ks * 32 + q * 8;
#pragma unroll
      for (int mt = 0; mt < 4; ++mt) {
        bf16x8 afr = *(const bf16x8*)&hb[mt * 16 + p][k0];
#pragma unroll
        for (int nt = 0; nt < 3; ++nt) {
          bf16x8 bfr = *(const bf16x8*)(w2T + (size_t)(wave * 48 + nt * 16 + p) * HID + ch * 64 + k0);
          accO[mt][nt] = MFMA16(afr, bfr, accO[mt][nt]);
        }
      }
    }
  }
  __syncthreads();

#pragma unroll
  for (int mt = 0; mt < 4; ++mt)
#pragma unroll
    for (int nt = 0; nt < 3; ++nt) {
      int col = wave * 48 + nt * 16 + p;
      float bias = b2[col];
#pragma unroll
      for (int r = 0; r < 4; ++r)
        xn[mt * 16 + q * 4 + r][col] = f2b(accO[mt][nt][r] + bias);
    }
  __syncthreads();

#pragma unroll
  for (int cg = 0; cg < 6; ++cg) {
    int chunk = (tid >> 6) + cg * 4;          // 0..23
    int txx = tid & 63;
    int c8 = chunk * 8;
    int xp = (x0 + txx + 252) & 255;
    u16x8 raw = *(const u16x8*)(x_mid + winrow + (size_t)(xp >> 3) * 12288 +
                                (size_t)(ip * 8 + (xp & 7)) * 192 + c8);
    u16x8 mo = *(const u16x8*)&xn[txx][c8];
#pragma unroll
    for (int t = 0; t < 8; ++t) {
      out[(((size_t)(b * DIM + c8 + t)) << 16) + (y << 8) + x0 + txx] =
          b2f(raw[t]) + b2f(mo[t]);
    }
  }
}

// ---------------- host launcher --------------------------------------------
extern "C" void kernel_launch(void* const* d_in, const int* in_sizes, int n_in,
                              void* d_out, int out_size, void* d_ws, size_t ws_size,
                              hipStream_t stream) {
  const float* x      = (const float*)d_in[0];
  const float* qkv_w  = (const float*)d_in[1];
  const float* qkv_b  = (const float*)d_in[2];
  const float* proj_w = (const float*)d_in[3];
  const float* proj_b = (const float*)d_in[4];
  const float* n1w    = (const float*)d_in[5];
  const float* n1b    = (const float*)d_in[6];
  const float* n2w    = (const float*)d_in[7];
  const float* n2b    = (const float*)d_in[8];
  const float* mlp_w1 = (const float*)d_in[9];
  const float* mlp_b1 = (const float*)d_in[10];
  const float* mlp_w2 = (const float*)d_in[11];
  const float* mlp_b2 = (const float*)d_in[12];
  float* out = (float*)d_out;

  char* ws = (char*)d_ws;
  const size_t XMID_B = (size_t)NWIN * 64 * DIM * 2;          // 100663296
  ushort_t* buf   = (ushort_t*)ws;     // x_win -> O -> x_mid (same region)
  char* wp = ws + XMID_B;
  ushort_t* projT = (ushort_t*)(wp);                 // 73728
  ushort_t* w2T   = (ushort_t*)(wp + 73728);         // 294912
  ushort_t* qkvTb = (ushort_t*)(wp + 368640);        // 884736
  float*    qkvbb = (float*)   (wp + 1253376);       // 9216
  ushort_t* w1b   = (ushort_t*)(wp + 1262592);       // 1179648
  float*    b1b   = (float*)   (wp + 2442240);       // 12288
  float* partial  = (float*)   (wp + 2454528);       // 16384
  float* stats1   = (float*)   (wp + 2470912);       // 256
  float* stats2   = (float*)   (wp + 2471168);       // 256
  float2* gpart   = (float2*)  (wp + 2471424);       // 262144

  transpose_w<<<(192 * 192 + 255) / 256, 256, 0, stream>>>(proj_w, projT, 192, 192);
  transpose_w<<<(192 * 768 + 255) / 256, 256, 0, stream>>>(mlp_w2, w2T, 768, 192);

  gn_stats1_f32<<<32 * 64, 256, 0, stream>>>(x, partial);
  gn_stats2<<<32, 64, 0, stream>>>(partial, stats1);

  win_x<<<NWIN, 256, 0, stream>>>(x, buf);

  fold_w<<<4 * 36, 256, 0, stream>>>(qkv_w, qkv_b, stats1, n1w, n1b,
                                     qkvTb, qkvbb, 576);

  attn_kernel<<<NWIN, 768, 0, stream>>>(buf, qkvTb, qkvbb, buf);

  proj_kernel<<<NWIN, 256, 0, stream>>>(buf, projT, proj_b, x, gpart);

  gn2_reduce<<<32, 64, 0, stream>>>(gpart, stats2);

  fold_w<<<4 * 48, 256, 0, stream>>>(mlp_w1, mlp_b1, stats2, n2w, n2b,
                                     w1b, b1b, 768);

  mlp_kernel<<<NWIN, 256, 0, stream>>>(buf, w1b, b1b, w2T, mlp_b2, out);
}

// Round 15
// 945.183 us; speedup vs baseline: 1.0842x; 1.0842x over previous
//
#include <hip/hip_runtime.h>

typedef unsigned short ushort_t;
typedef __bf16 bf16x8 __attribute__((ext_vector_type(8)));
typedef float f32x4 __attribute__((ext_vector_type(4)));
typedef unsigned short u16x8 __attribute__((ext_vector_type(8)));
typedef unsigned short u16x4 __attribute__((ext_vector_type(4)));

#define MFMA16(a, b, c) __builtin_amdgcn_mfma_f32_16x16x32_bf16(a, b, c, 0, 0, 0)

#define DIM 192
#define HEADS 6
#define GROUPS 8
#define CPG 24
#define HID 768
#define NWIN 4096
#define GN_N 1572864
#define SCALE 0.17677669529663687f

__device__ __forceinline__ ushort_t f2b(float f) {
  __bf16 h = (__bf16)f;
  return __builtin_bit_cast(unsigned short, h);
}
__device__ __forceinline__ float b2f(ushort_t u) {
  union { unsigned int u; float f; } v; v.u = ((unsigned int)u) << 16;
  return v.f;
}

// 8x8 transpose across lane-bits 3..5 vs register index (involution).
__device__ __forceinline__ void xpose8(ushort_t V[8], int C3) {
#pragma unroll
  for (int bb = 0; bb < 3; ++bb) {
    const int m = 1 << bb;
    int tt[8];
#pragma unroll
    for (int j = 0; j < 8; ++j) tt[j] = __shfl_xor((int)V[j], m << 3, 64);
#pragma unroll
    for (int j = 0; j < 8; ++j)
      if (((j >> bb) & 1) != ((C3 >> bb) & 1)) V[j] = (ushort_t)tt[j ^ m];
  }
}

// ---------------- weight transpose + bf16 convert: out[n][k] = in[k][n] ----
__global__ __launch_bounds__(256) void transpose_w(const float* __restrict__ in,
                                                   ushort_t* __restrict__ out,
                                                   int K, int N) {
  int id = blockIdx.x * 256 + threadIdx.x;
  if (id >= K * N) return;
  int n = id / K, k = id - n * K;
  out[id] = f2b(in[k * N + n]);
}

// ---------------- fold GroupNorm affine into weights, per batch ------------
__global__ __launch_bounds__(256) void fold_w(
    const float* __restrict__ wsrc, const float* __restrict__ bsrc,
    const float* __restrict__ stats,
    const float* __restrict__ nw, const float* __restrict__ nb,
    ushort_t* __restrict__ wdst, float* __restrict__ bdst, int N) {
  int nb16 = N >> 4;
  int blk = blockIdx.x;
  int bb = blk / nb16, ng = blk - bb * nb16;
  int tid = threadIdx.x;
  int colL = tid >> 4, kq = tid & 15;
  int col = ng * 16 + colL;
  ushort_t* wout = wdst + ((size_t)bb * N + col) * 192;
  float acc = 0.f;
#pragma unroll
  for (int j = 0; j < 12; ++j) {
    int k = kq * 12 + j;
    int g = k / 24;
    float mean = stats[(bb * 8 + g) * 2], rstd = stats[(bb * 8 + g) * 2 + 1];
    float gw = nw[k] * rstd;
    float gb = nb[k] - mean * gw;
    float w_ = wsrc[(size_t)k * N + col];
    wout[k] = f2b(gw * w_);
    acc += gb * w_;
  }
  for (int m = 1; m < 16; m <<= 1) acc += __shfl_xor(acc, m);
  if (kq == 0) bdst[bb * N + col] = bsrc[col] + acc;
}

// ---------------- GN reduce: per-window partials -> stats ------------------
__global__ __launch_bounds__(64) void gn2_reduce(const float2* __restrict__ gpart,
                                                 float* __restrict__ stats) {
  int bid = blockIdx.x;            // b*8 + g
  int b = bid >> 3, g = bid & 7;
  int lane = threadIdx.x;
  float s = 0.f, s2 = 0.f;
  for (int w = lane; w < 1024; w += 64) {
    float2 v = gpart[((size_t)b * 1024 + w) * 8 + g];
    s += v.x; s2 += v.y;
  }
  for (int m = 1; m < 64; m <<= 1) { s += __shfl_xor(s, m); s2 += __shfl_xor(s2, m); }
  if (lane == 0) {
    const float invN = 1.0f / (float)GN_N;
    float mean = s * invN;
    float var = s2 * invN - mean * mean;
    stats[bid * 2] = mean;
    stats[bid * 2 + 1] = rsqrtf(var + 1e-5f);
  }
}

// ---------------- win_x: shift + windowize x -> buf + GN1 partials ---------
// GN1 affine folds into qkv weights; stats computed here on bf16 values
// (delta vs fp32 stats ~1e-5 relative; well inside error budget).
__global__ __launch_bounds__(256) void win_x(
    const float* __restrict__ x, ushort_t* __restrict__ buf,
    float2* __restrict__ gpart) {
  int w = blockIdx.x;
  int b = w >> 10, wh = (w >> 5) & 31, ww = w & 31;
  int tid = threadIdx.x;
  int wave = tid >> 6, lane = tid & 63;
  int C3 = lane >> 3, I = lane & 7;

  __shared__ __align__(16) ushort_t tile[64][200];  // later aliased by red

  int px0 = (ww << 3) + 4;
  int px1 = (px0 + 4) & 255;

#pragma unroll
  for (int it = 0; it < 6; ++it) {
    int u = it * 256 + tid;
    int c = u >> 3, i = u & 7;
    int py = ((wh << 3) + i + 4) & 255;
    const float* src = x + (((size_t)(b * DIM + c)) << 16) + (py << 8);
    float4 ra = *(const float4*)(src + px0);
    float4 rb = *(const float4*)(src + px1);
    ushort_t V[8];
    V[0] = f2b(ra.x); V[1] = f2b(ra.y); V[2] = f2b(ra.z); V[3] = f2b(ra.w);
    V[4] = f2b(rb.x); V[5] = f2b(rb.y); V[6] = f2b(rb.z); V[7] = f2b(rb.w);
    xpose8(V, C3);   // V[j] = x(channel cbase+j, token I*8+C3)
    u16x8 wv;
#pragma unroll
    for (int j = 0; j < 8; ++j) wv[j] = V[j];
    int cbase = it * 32 + wave * 8;
    *(u16x8*)&tile[I * 8 + C3][cbase] = wv;
  }
  __syncthreads();

  ushort_t* bw = buf + (size_t)w * 12288;
  float sacc[6], s2acc[6];
#pragma unroll
  for (int it = 0; it < 6; ++it) {
    int u = it * 256 + tid;
    int token = u / 24, cv = u - token * 24;
    u16x8 v = *(const u16x8*)&tile[token][cv * 8];
    *(u16x8*)&bw[u * 8] = v;
    float s_ = 0.f, s2_ = 0.f;
#pragma unroll
    for (int t = 0; t < 8; ++t) { float f = b2f(v[t]); s_ += f; s2_ += f * f; }
    sacc[it] = s_; s2acc[it] = s2_;
  }
  __syncthreads();   // all tile reads done; red aliases tile

  float2* red = (float2*)&tile[0][0];   // 12288 B <= 25600 B
#pragma unroll
  for (int it = 0; it < 6; ++it)
    red[it * 256 + tid] = make_float2(sacc[it], s2acc[it]);
  __syncthreads();

  for (int g = wave; g < 8; g += 4) {
    float s_ = 0.f, s2_ = 0.f;
#pragma unroll
    for (int j = 0; j < 3; ++j) {
      float2 t_ = red[lane * 24 + g * 3 + j];
      s_ += t_.x; s2_ += t_.y;
    }
    for (int m = 1; m < 64; m <<= 1) { s_ += __shfl_xor(s_, m); s2_ += __shfl_xor(s2_, m); }
    if (lane == 0) gpart[(size_t)w * 8 + g] = make_float2(s_, s2_);
  }
}

// One qkv+attention pass for heads PH*2, PH*2+1.  PH literal (rule #20).
// Direct stores from named acc0..acc3 (keeps VGPR <= 64: 2 blocks/CU).
#define QKV_ATTN_PASS(PH)                                                      \
  {                                                                            \
    {                                                                          \
      int sec = wave >> 2;              /* 0=q 1=k 2=v */                      \
      int tloc = wave & 3;                                                     \
      int cols16 = sec * 192 + (PH) * 64 + tloc * 16;                          \
      int lh = tloc >> 1;                                                      \
      int d = ((tloc & 1) << 4) + p;                                           \
      f32x4 acc0 = zz, acc1 = zz, acc2 = zz, acc3 = zz;                        \
      _Pragma("unroll")                                                        \
      for (int ks = 0; ks < 6; ++ks) {                                         \
        int k0 = ks * 32 + q8 * 8;                                             \
        bf16x8 bfr = *(const bf16x8*)(qkvT + (size_t)(cols16 + p) * DIM + k0); \
        acc0 = MFMA16(*(const bf16x8*)&tile[0 * 16 + p][k0], bfr, acc0);       \
        acc1 = MFMA16(*(const bf16x8*)&tile[1 * 16 + p][k0], bfr, acc1);       \
        acc2 = MFMA16(*(const bf16x8*)&tile[2 * 16 + p][k0], bfr, acc2);       \
        acc3 = MFMA16(*(const bf16x8*)&tile[3 * 16 + p][k0], bfr, acc3);       \
      }                                                                        \
      float bias = qkv_b[cols16 + p];                                          \
      if (sec == 0) {                                                          \
        int base = q8 * 4;                                                     \
        _Pragma("unroll")                                                      \
        for (int r = 0; r < 4; ++r) {                                          \
          qkP[lh][(0 * 16 + base + r) * 40 + d] = f2b((acc0[r] + bias) * SCALE); \
          qkP[lh][(1 * 16 + base + r) * 40 + d] = f2b((acc1[r] + bias) * SCALE); \
          qkP[lh][(2 * 16 + base + r) * 40 + d] = f2b((acc2[r] + bias) * SCALE); \
          qkP[lh][(3 * 16 + base + r) * 40 + d] = f2b((acc3[r] + bias) * SCALE); \
        }                                                                      \
      } else if (sec == 1) {                                                   \
        int base = q8 * 4;                                                     \
        _Pragma("unroll")                                                      \
        for (int r = 0; r < 4; ++r) {                                          \
          qkP[lh][2560 + (0 * 16 + base + r) * 40 + d] = f2b(acc0[r] + bias);  \
          qkP[lh][2560 + (1 * 16 + base + r) * 40 + d] = f2b(acc1[r] + bias);  \
          qkP[lh][2560 + (2 * 16 + base + r) * 40 + d] = f2b(acc2[r] + bias);  \
          qkP[lh][2560 + (3 * 16 + base + r) * 40 + d] = f2b(acc3[r] + bias);  \
        }                                                                      \
      } else {                                                                 \
        u16x4 v0, v1, v2, v3;                                                  \
        _Pragma("unroll")                                                      \
        for (int r = 0; r < 4; ++r) {                                          \
          v0[r] = f2b(acc0[r] + bias);                                         \
          v1[r] = f2b(acc1[r] + bias);                                         \
          v2[r] = f2b(acc2[r] + bias);                                         \
          v3[r] = f2b(acc3[r] + bias);                                         \
        }                                                                      \
        int base = d * 72 + q8 * 4;                                            \
        *(u16x4*)&vT[lh][base + 0]  = v0;                                      \
        *(u16x4*)&vT[lh][base + 16] = v1;                                      \
        *(u16x4*)&vT[lh][base + 32] = v2;                                      \
        *(u16x4*)&vT[lh][base + 48] = v3;                                      \
      }                                                                        \
    }                                                                          \
    __syncthreads(); /* B2 */                                                  \
    {                                                                          \
      int lh = (wave >> 2) & 1, quad = wave & 3;                               \
      int rb_ = quad << 4;                                                     \
      int k0 = q8 * 8;                                                         \
      f32x4 s0 = zz, s1 = zz, s2 = zz, s3 = zz;                                \
      if (wave < 8) {                                                          \
        const ushort_t* qh = &qkP[lh][0];                                      \
        const ushort_t* kh = &qkP[lh][2560];                                   \
        bf16x8 aq = *(const bf16x8*)&qh[(rb_ + p) * 40 + k0];                  \
        bf16x8 bk0 = *(const bf16x8*)&kh[(0 + p) * 40 + k0];                   \
        bf16x8 bk1 = *(const bf16x8*)&kh[(16 + p) * 40 + k0];                  \
        bf16x8 bk2 = *(const bf16x8*)&kh[(32 + p) * 40 + k0];                  \
        bf16x8 bk3 = *(const bf16x8*)&kh[(48 + p) * 40 + k0];                  \
        s0 = MFMA16(aq, bk0, zz);                                              \
        s1 = MFMA16(aq, bk1, zz);                                              \
        s2 = MFMA16(aq, bk2, zz);                                              \
        s3 = MFMA16(aq, bk3, zz);                                              \
      }                                                                        \
      __syncthreads(); /* B3: q/k reads done before P overwrite */             \
      if (wave < 8) {                                                          \
        ushort_t* Ph = &qkP[lh][0];                                            \
        _Pragma("unroll")                                                      \
        for (int r = 0; r < 4; ++r) {                                          \
          float m = fmaxf(fmaxf(s0[r], s1[r]), fmaxf(s2[r], s3[r]));           \
          for (int msk = 1; msk < 16; msk <<= 1) m = fmaxf(m, __shfl_xor(m, msk)); \
          float e0 = __expf(s0[r] - m);                                        \
          float e1 = __expf(s1[r] - m);                                        \
          float e2 = __expf(s2[r] - m);                                        \
          float e3 = __expf(s3[r] - m);                                        \
          float sum = e0 + e1 + e2 + e3;                                       \
          for (int msk = 1; msk < 16; msk <<= 1) sum += __shfl_xor(sum, msk);  \
          float inv = 1.0f / sum;                                              \
          int row = rb_ + q8 * 4 + r;                                          \
          Ph[row * 72 + 0 + p]  = f2b(e0 * inv);                               \
          Ph[row * 72 + 16 + p] = f2b(e1 * inv);                               \
          Ph[row * 72 + 32 + p] = f2b(e2 * inv);                               \
          Ph[row * 72 + 48 + p] = f2b(e3 * inv);                               \
        }                                                                      \
        f32x4 o0 = zz, o1 = zz;                                                \
        _Pragma("unroll")                                                      \
        for (int ks = 0; ks < 2; ++ks) {                                       \
          int kk = ks * 32 + k0;                                               \
          bf16x8 bv0 = *(const bf16x8*)&vT[lh][(0 + p) * 72 + kk];             \
          bf16x8 bv1 = *(const bf16x8*)&vT[lh][(16 + p) * 72 + kk];            \
          bf16x8 ap = *(const bf16x8*)&Ph[(rb_ + p) * 72 + kk];                \
          o0 = MFMA16(ap, bv0, o0);                                            \
          o1 = MFMA16(ap, bv1, o1);                                            \
        }                                                                      \
        size_t ob = (size_t)w * 12288 + (size_t)(rb_ + q8 * 4) * 192 +         \
                    ((PH) * 2 + lh) * 32 + p;                                  \
        _Pragma("unroll")                                                      \
        for (int r = 0; r < 4; ++r) {                                          \
          obuf[ob + (size_t)r * 192]      = f2b(o0[r]);                        \
          obuf[ob + (size_t)r * 192 + 16] = f2b(o1[r]);                        \
        }                                                                      \
      }                                                                        \
    }                                                                          \
  }

// ---------------- K_a: qkv + attention (raw-x win in; O in place) ----------
__global__ __launch_bounds__(768, 3) void attn_kernel(
    const ushort_t* __restrict__ buf_xn,
    const ushort_t* __restrict__ qkvTb_, const float* __restrict__ qkvbb_,
    ushort_t* __restrict__ obuf) {
  int w = blockIdx.x;
  int tid = threadIdx.x;
  int wave = tid >> 6, lane = tid & 63;
  int p = lane & 15, q8 = lane >> 4;

  const ushort_t* qkvT = qkvTb_ + (size_t)(w >> 10) * 110592;   // 576*192
  const float* qkv_b = qkvbb_ + (w >> 10) * 576;

  __shared__ __align__(16) ushort_t tile[64][200];  // x win (token-major)
  __shared__ __align__(16) ushort_t qkP[2][5120];   // q|k -> P, per head
  __shared__ __align__(16) ushort_t vT[2][2304];    // v^T [32][72]

  const ushort_t* bw = buf_xn + (size_t)w * 12288;
#pragma unroll
  for (int it = 0; it < 2; ++it) {
    int u = it * 768 + tid;
    int token = u / 24, cv = u - token * 24;
    *(u16x8*)&tile[token][cv * 8] = *(const u16x8*)&bw[u * 8];
  }
  __syncthreads();   // B1

  const f32x4 zz = {0.f, 0.f, 0.f, 0.f};

  QKV_ATTN_PASS(0)
  __syncthreads();   // B4
  QKV_ATTN_PASS(1)
  __syncthreads();   // B4
  QKV_ATTN_PASS(2)
}

// ---------------- K_b: proj GEMM + residual-1 -> x_mid (in place) ----------
// LDS = otile only (25600 B); red aliases otile after it is dead.
__global__ __launch_bounds__(256) void proj_kernel(
    ushort_t* __restrict__ buf,           // in: O, out: x_mid (windowed)
    const ushort_t* __restrict__ projT, const float* __restrict__ proj_b,
    const float* __restrict__ x, float2* __restrict__ gpart) {
  int w = blockIdx.x;
  int b = w >> 10, wh = (w >> 5) & 31, ww = w & 31;
  int tid = threadIdx.x;
  int wave = tid >> 6, lane = tid & 63;
  int p = lane & 15, q8 = lane >> 4;
  int C3 = lane >> 3, I = lane & 7;

  __shared__ __align__(16) ushort_t otile[64][200];  // O -> proj-out -> resid -> red

  ushort_t* bw = buf + (size_t)w * 12288;

#pragma unroll
  for (int it = 0; it < 6; ++it) {
    int idx = (it * 256 + tid) * 8;
    int t = idx / 192, c = idx - t * 192;
    *(u16x8*)&otile[t][c] = *(const u16x8*)&bw[idx];
  }
  __syncthreads();

  const f32x4 zz = {0.f, 0.f, 0.f, 0.f};
  f32x4 prr[3][4];
#pragma unroll
  for (int rd = 0; rd < 3; ++rd) {
    int col = rd * 64 + wave * 16 + p;
#pragma unroll
    for (int mt = 0; mt < 4; ++mt) prr[rd][mt] = zz;
#pragma unroll
    for (int ks = 0; ks < 6; ++ks) {
      int k0 = ks * 32 + q8 * 8;
      bf16x8 bfr = *(const bf16x8*)(projT + (size_t)col * DIM + k0);
      prr[rd][0] = MFMA16(*(const bf16x8*)&otile[0 * 16 + p][k0], bfr, prr[rd][0]);
      prr[rd][1] = MFMA16(*(const bf16x8*)&otile[1 * 16 + p][k0], bfr, prr[rd][1]);
      prr[rd][2] = MFMA16(*(const bf16x8*)&otile[2 * 16 + p][k0], bfr, prr[rd][2]);
      prr[rd][3] = MFMA16(*(const bf16x8*)&otile[3 * 16 + p][k0], bfr, prr[rd][3]);
    }
  }
  __syncthreads();

#pragma unroll
  for (int rd = 0; rd < 3; ++rd) {
    int col = rd * 64 + wave * 16 + p;
    float bias = proj_b[col];
#pragma unroll
    for (int mt = 0; mt < 4; ++mt)
#pragma unroll
      for (int r = 0; r < 4; ++r)
        otile[mt * 16 + q8 * 4 + r][col] = f2b(prr[rd][mt][r] + bias);
  }
  __syncthreads();

  int px0 = (ww << 3) + 4;
  int px1 = (px0 + 4) & 255;

#pragma unroll
  for (int it = 0; it < 6; ++it) {
    int u = it * 256 + tid;
    int c = u >> 3, i = u & 7;
    int cbase = it * 32 + wave * 8;
    u16x8 rr = *(const u16x8*)&otile[I * 8 + C3][cbase];
    ushort_t V[8];
#pragma unroll
    for (int j = 0; j < 8; ++j) V[j] = rr[j];
    xpose8(V, C3);
    int py = ((wh << 3) + i + 4) & 255;
    const float* src = x + (((size_t)(b * DIM + c)) << 16) + (py << 8);
    float4 ra = *(const float4*)(src + px0);
    V[0] = f2b(ra.x + b2f(V[0]));
    V[1] = f2b(ra.y + b2f(V[1]));
    V[2] = f2b(ra.z + b2f(V[2]));
    V[3] = f2b(ra.w + b2f(V[3]));
    float4 rb2 = *(const float4*)(src + px1);
    V[4] = f2b(rb2.x + b2f(V[4]));
    V[5] = f2b(rb2.y + b2f(V[5]));
    V[6] = f2b(rb2.z + b2f(V[6]));
    V[7] = f2b(rb2.w + b2f(V[7]));
    xpose8(V, C3);
    u16x8 wv;
#pragma unroll
    for (int j = 0; j < 8; ++j) wv[j] = V[j];
    *(u16x8*)&otile[I * 8 + C3][cbase] = wv;
  }
  __syncthreads();

  // coalesced write back + delayed GN2 partials (regs, then red over otile)
  float sacc[6], s2acc[6];
#pragma unroll
  for (int it = 0; it < 6; ++it) {
    int u = it * 256 + tid;
    int token = u / 24, cv = u - token * 24;
    u16x8 v = *(const u16x8*)&otile[token][cv * 8];
    *(u16x8*)&bw[u * 8] = v;
    float s_ = 0.f, s2_ = 0.f;
#pragma unroll
    for (int t = 0; t < 8; ++t) { float f = b2f(v[t]); s_ += f; s2_ += f * f; }
    sacc[it] = s_; s2acc[it] = s2_;
  }
  __syncthreads();   // all otile reads done; red aliases otile

  float2* red = (float2*)&otile[0][0];   // 12288 B <= 25600 B
#pragma unroll
  for (int it = 0; it < 6; ++it)
    red[it * 256 + tid] = make_float2(sacc[it], s2acc[it]);
  __syncthreads();

  for (int g = wave; g < 8; g += 4) {
    float s_ = 0.f, s2_ = 0.f;
#pragma unroll
    for (int j = 0; j < 3; ++j) {
      float2 t_ = red[lane * 24 + g * 3 + j];
      s_ += t_.x; s2_ += t_.y;
    }
    for (int m = 1; m < 64; m <<= 1) { s_ += __shfl_xor(s_, m); s2_ += __shfl_xor(s2_, m); }
    if (lane == 0) gpart[(size_t)w * 8 + g] = make_float2(s_, s2_);
  }
}

// ---------------- fused MLP + residual2 (GN2 folded into W1') --------------
__global__ __launch_bounds__(256, 4) void mlp_kernel(
    const ushort_t* __restrict__ x_mid,
    const ushort_t* __restrict__ w1b, const float* __restrict__ b1b,
    const ushort_t* __restrict__ w2T, const float* __restrict__ b2,
    float* __restrict__ out) {
  int bid = blockIdx.x;
  int b = bid >> 10, y = (bid >> 2) & 255, xq = bid & 3;
  int x0 = xq * 64;
  int tid = threadIdx.x;
  int wave = tid >> 6, lane = tid & 63;
  int p = lane & 15, q = lane >> 4;

  __shared__ ushort_t xn[64][200];   // xm tile, later mlp-out staging
  __shared__ ushort_t hb[64][72];    // hidden chunk [token][hid]

  const ushort_t* w1T = w1b + (size_t)b * 147456;   // 768*192
  const float* b1 = b1b + b * 768;

  int yp = (y + 252) & 255;          // (y - 4) mod 256
  int whp = yp >> 3, ip = yp & 7;
  size_t winrow = ((size_t)b * 1024 + (size_t)whp * 32) * 12288;

  for (int u = tid; u < 1536; u += 256) {
    int tx = u / 24, ch = u - tx * 24;
    int c8 = ch * 8;
    int xp = (x0 + tx + 252) & 255;  // (x - 4) mod 256
    *(u16x8*)&xn[tx][c8] =
        *(const u16x8*)(x_mid + winrow + (size_t)(xp >> 3) * 12288 +
                        (size_t)(ip * 8 + (xp & 7)) * 192 + c8);
  }
  __syncthreads();

  const f32x4 zz = {0.f, 0.f, 0.f, 0.f};
  f32x4 accO[4][3];
#pragma unroll
  for (int mt = 0; mt < 4; ++mt)
#pragma unroll
    for (int nt = 0; nt < 3; ++nt) accO[mt][nt] = zz;

  for (int ch = 0; ch < 12; ++ch) {
    int hcol16 = ch * 64 + wave * 16;
    f32x4 a1[4];
#pragma unroll
    for (int mt = 0; mt < 4; ++mt) a1[mt] = zz;
#pragma unroll
    for (int ks = 0; ks < 6; ++ks) {
      int k0 = ks * 32 + q * 8;
      bf16x8 wfr = *(const bf16x8*)(w1T + (size_t)(hcol16 + p) * DIM + k0);
#pragma unroll
      for (int mt = 0; mt < 4; ++mt) {
        bf16x8 afr = *(const bf16x8*)&xn[mt * 16 + p][k0];
        a1[mt] = MFMA16(wfr, afr, a1[mt]);   // swapped: weights=rows, tokens=cols
      }
    }
    float4 bb = *(const float4*)&b1[hcol16 + q * 4];
    if (ch) __syncthreads();
#pragma unroll
    for (int mt = 0; mt < 4; ++mt) {
      u16x4 hv;
#pragma unroll
      for (int r = 0; r < 4; ++r) {
        float vv = a1[mt][r] + ((const float*)&bb)[r];
        float g = vv / (1.0f + __expf(-1.702f * vv));   // sigmoid-GELU
        hv[r] = f2b(g);
      }
      *(u16x4*)&hb[mt * 16 + p][wave * 16 + q * 4] = hv;
    }
    __syncthreads();
#pragma unroll
    for (int ks = 0; ks < 2; ++ks) {
      int k0 = ks * 32 + q * 8;
#pragma unroll
      for (int mt = 0; mt < 4; ++mt) {
        bf16x8 afr = *(const bf16x8*)&hb[mt * 16 + p][k0];
#pragma unroll
        for (int nt = 0; nt < 3; ++nt) {
          bf16x8 bfr = *(const bf16x8*)(w2T + (size_t)(wave * 48 + nt * 16 + p) * HID + ch * 64 + k0);
          accO[mt][nt] = MFMA16(afr, bfr, accO[mt][nt]);
        }
      }
    }
  }
  __syncthreads();

#pragma unroll
  for (int mt = 0; mt < 4; ++mt)
#pragma unroll
    for (int nt = 0; nt < 3; ++nt) {
      int col = wave * 48 + nt * 16 + p;
      float bias = b2[col];
#pragma unroll
      for (int r = 0; r < 4; ++r)
        xn[mt * 16 + q * 4 + r][col] = f2b(accO[mt][nt][r] + bias);
    }
  __syncthreads();

#pragma unroll
  for (int cg = 0; cg < 6; ++cg) {
    int chunk = (tid >> 6) + cg * 4;          // 0..23
    int txx = tid & 63;
    int c8 = chunk * 8;
    int xp = (x0 + txx + 252) & 255;
    u16x8 raw = *(const u16x8*)(x_mid + winrow + (size_t)(xp >> 3) * 12288 +
                                (size_t)(ip * 8 + (xp & 7)) * 192 + c8);
    u16x8 mo = *(const u16x8*)&xn[txx][c8];
#pragma unroll
    for (int t = 0; t < 8; ++t) {
      out[(((size_t)(b * DIM + c8 + t)) << 16) + (y << 8) + x0 + txx] =
          b2f(raw[t]) + b2f(mo[t]);
    }
  }
}

// ---------------- host launcher --------------------------------------------
extern "C" void kernel_launch(void* const* d_in, const int* in_sizes, int n_in,
                              void* d_out, int out_size, void* d_ws, size_t ws_size,
                              hipStream_t stream) {
  const float* x      = (const float*)d_in[0];
  const float* qkv_w  = (const float*)d_in[1];
  const float* qkv_b  = (const float*)d_in[2];
  const float* proj_w = (const float*)d_in[3];
  const float* proj_b = (const float*)d_in[4];
  const float* n1w    = (const float*)d_in[5];
  const float* n1b    = (const float*)d_in[6];
  const float* n2w    = (const float*)d_in[7];
  const float* n2b    = (const float*)d_in[8];
  const float* mlp_w1 = (const float*)d_in[9];
  const float* mlp_b1 = (const float*)d_in[10];
  const float* mlp_w2 = (const float*)d_in[11];
  const float* mlp_b2 = (const float*)d_in[12];
  float* out = (float*)d_out;

  char* ws = (char*)d_ws;
  const size_t XMID_B = (size_t)NWIN * 64 * DIM * 2;          // 100663296
  ushort_t* buf   = (ushort_t*)ws;     // x_win -> O -> x_mid (same region)
  char* wp = ws + XMID_B;
  ushort_t* projT = (ushort_t*)(wp);                 // 73728
  ushort_t* w2T   = (ushort_t*)(wp + 73728);         // 294912
  ushort_t* qkvTb = (ushort_t*)(wp + 368640);        // 884736
  float*    qkvbb = (float*)   (wp + 1253376);       // 9216
  ushort_t* w1b   = (ushort_t*)(wp + 1262592);       // 1179648
  float*    b1b   = (float*)   (wp + 2442240);       // 12288
  float* stats1   = (float*)   (wp + 2454528);       // 256
  float* stats2   = (float*)   (wp + 2454784);       // 256
  float2* gpart   = (float2*)  (wp + 2455040);       // 262144

  transpose_w<<<(192 * 192 + 255) / 256, 256, 0, stream>>>(proj_w, projT, 192, 192);
  transpose_w<<<(192 * 768 + 255) / 256, 256, 0, stream>>>(mlp_w2, w2T, 768, 192);

  win_x<<<NWIN, 256, 0, stream>>>(x, buf, gpart);

  gn2_reduce<<<32, 64, 0, stream>>>(gpart, stats1);

  fold_w<<<4 * 36, 256, 0, stream>>>(qkv_w, qkv_b, stats1, n1w, n1b,
                                     qkvTb, qkvbb, 576);

  attn_kernel<<<NWIN, 768, 0, stream>>>(buf, qkvTb, qkvbb, buf);

  proj_kernel<<<NWIN, 256, 0, stream>>>(buf, projT, proj_b, x, gpart);

  gn2_reduce<<<32, 64, 0, stream>>>(gpart, stats2);

  fold_w<<<4 * 48, 256, 0, stream>>>(mlp_w1, mlp_b1, stats2, n2w, n2b,
                                     w1b, b1b, 768);

  mlp_kernel<<<NWIN, 256, 0, stream>>>(buf, w1b, b1b, w2T, mlp_b2, out);
}

// Round 16
// 767.441 us; speedup vs baseline: 1.3354x; 1.2316x over previous
//
#include <hip/hip_runtime.h>

typedef unsigned short ushort_t;
typedef __bf16 bf16x8 __attribute__((ext_vector_type(8)));
typedef float f32x4 __attribute__((ext_vector_type(4)));
typedef unsigned short u16x8 __attribute__((ext_vector_type(8)));
typedef unsigned short u16x4 __attribute__((ext_vector_type(4)));

#define MFMA16(a, b, c) __builtin_amdgcn_mfma_f32_16x16x32_bf16(a, b, c, 0, 0, 0)

#define DIM 192
#define HEADS 6
#define GROUPS 8
#define CPG 24
#define HID 768
#define NWIN 4096
#define GN_N 1572864
#define SCALE 0.17677669529663687f

__device__ __forceinline__ ushort_t f2b(float f) {
  __bf16 h = (__bf16)f;
  return __builtin_bit_cast(unsigned short, h);
}
__device__ __forceinline__ float b2f(ushort_t u) {
  union { unsigned int u; float f; } v; v.u = ((unsigned int)u) << 16;
  return v.f;
}

// 8x8 transpose across lane-bits 3..5 vs register index (involution).
__device__ __forceinline__ void xpose8(ushort_t V[8], int C3) {
#pragma unroll
  for (int bb = 0; bb < 3; ++bb) {
    const int m = 1 << bb;
    int tt[8];
#pragma unroll
    for (int j = 0; j < 8; ++j) tt[j] = __shfl_xor((int)V[j], m << 3, 64);
#pragma unroll
    for (int j = 0; j < 8; ++j)
      if (((j >> bb) & 1) != ((C3 >> bb) & 1)) V[j] = (ushort_t)tt[j ^ m];
  }
}

// ---------------- weight transpose + bf16 convert: out[n][k] = in[k][n] ----
__global__ __launch_bounds__(256) void transpose_w(const float* __restrict__ in,
                                                   ushort_t* __restrict__ out,
                                                   int K, int N) {
  int id = blockIdx.x * 256 + threadIdx.x;
  if (id >= K * N) return;
  int n = id / K, k = id - n * K;
  out[id] = f2b(in[k * N + n]);
}

// ---------------- fold GroupNorm affine into weights, per batch ------------
__global__ __launch_bounds__(256) void fold_w(
    const float* __restrict__ wsrc, const float* __restrict__ bsrc,
    const float* __restrict__ stats,
    const float* __restrict__ nw, const float* __restrict__ nb,
    ushort_t* __restrict__ wdst, float* __restrict__ bdst, int N) {
  int nb16 = N >> 4;
  int blk = blockIdx.x;
  int bb = blk / nb16, ng = blk - bb * nb16;
  int tid = threadIdx.x;
  int colL = tid >> 4, kq = tid & 15;
  int col = ng * 16 + colL;
  ushort_t* wout = wdst + ((size_t)bb * N + col) * 192;
  float acc = 0.f;
#pragma unroll
  for (int j = 0; j < 12; ++j) {
    int k = kq * 12 + j;
    int g = k / 24;
    float mean = stats[(bb * 8 + g) * 2], rstd = stats[(bb * 8 + g) * 2 + 1];
    float gw = nw[k] * rstd;
    float gb = nb[k] - mean * gw;
    float w_ = wsrc[(size_t)k * N + col];
    wout[k] = f2b(gw * w_);
    acc += gb * w_;
  }
  for (int m = 1; m < 16; m <<= 1) acc += __shfl_xor(acc, m);
  if (kq == 0) bdst[bb * N + col] = bsrc[col] + acc;
}

// ---------------- GN reduce: per-window partials -> stats ------------------
__global__ __launch_bounds__(64) void gn2_reduce(const float2* __restrict__ gpart,
                                                 float* __restrict__ stats) {
  int bid = blockIdx.x;            // b*8 + g
  int b = bid >> 3, g = bid & 7;
  int lane = threadIdx.x;
  float s = 0.f, s2 = 0.f;
  for (int w = lane; w < 1024; w += 64) {
    float2 v = gpart[((size_t)b * 1024 + w) * 8 + g];
    s += v.x; s2 += v.y;
  }
  for (int m = 1; m < 64; m <<= 1) { s += __shfl_xor(s, m); s2 += __shfl_xor(s2, m); }
  if (lane == 0) {
    const float invN = 1.0f / (float)GN_N;
    float mean = s * invN;
    float var = s2 * invN - mean * mean;
    stats[bid * 2] = mean;
    stats[bid * 2 + 1] = rsqrtf(var + 1e-5f);
  }
}

// ---------------- win_x: shift + windowize x -> buf + GN1 partials ---------
__global__ __launch_bounds__(256) void win_x(
    const float* __restrict__ x, ushort_t* __restrict__ buf,
    float2* __restrict__ gpart) {
  int w = blockIdx.x;
  int b = w >> 10, wh = (w >> 5) & 31, ww = w & 31;
  int tid = threadIdx.x;
  int wave = tid >> 6, lane = tid & 63;
  int C3 = lane >> 3, I = lane & 7;

  __shared__ __align__(16) ushort_t tile[64][200];  // later aliased by red

  int px0 = (ww << 3) + 4;
  int px1 = (px0 + 4) & 255;

#pragma unroll
  for (int it = 0; it < 6; ++it) {
    int u = it * 256 + tid;
    int c = u >> 3, i = u & 7;
    int py = ((wh << 3) + i + 4) & 255;
    const float* src = x + (((size_t)(b * DIM + c)) << 16) + (py << 8);
    float4 ra = *(const float4*)(src + px0);
    float4 rb = *(const float4*)(src + px1);
    ushort_t V[8];
    V[0] = f2b(ra.x); V[1] = f2b(ra.y); V[2] = f2b(ra.z); V[3] = f2b(ra.w);
    V[4] = f2b(rb.x); V[5] = f2b(rb.y); V[6] = f2b(rb.z); V[7] = f2b(rb.w);
    xpose8(V, C3);   // V[j] = x(channel cbase+j, token I*8+C3)
    u16x8 wv;
#pragma unroll
    for (int j = 0; j < 8; ++j) wv[j] = V[j];
    int cbase = it * 32 + wave * 8;
    *(u16x8*)&tile[I * 8 + C3][cbase] = wv;
  }
  __syncthreads();

  ushort_t* bw = buf + (size_t)w * 12288;
  float sacc[6], s2acc[6];
#pragma unroll
  for (int it = 0; it < 6; ++it) {
    int u = it * 256 + tid;
    int token = u / 24, cv = u - token * 24;
    u16x8 v = *(const u16x8*)&tile[token][cv * 8];
    *(u16x8*)&bw[u * 8] = v;
    float s_ = 0.f, s2_ = 0.f;
#pragma unroll
    for (int t = 0; t < 8; ++t) { float f = b2f(v[t]); s_ += f; s2_ += f * f; }
    sacc[it] = s_; s2acc[it] = s2_;
  }
  __syncthreads();   // all tile reads done; red aliases tile

  float2* red = (float2*)&tile[0][0];   // 12288 B <= 25600 B
#pragma unroll
  for (int it = 0; it < 6; ++it)
    red[it * 256 + tid] = make_float2(sacc[it], s2acc[it]);
  __syncthreads();

  for (int g = wave; g < 8; g += 4) {
    float s_ = 0.f, s2_ = 0.f;
#pragma unroll
    for (int j = 0; j < 3; ++j) {
      float2 t_ = red[lane * 24 + g * 3 + j];
      s_ += t_.x; s2_ += t_.y;
    }
    for (int m = 1; m < 64; m <<= 1) { s_ += __shfl_xor(s_, m); s2_ += __shfl_xor(s2_, m); }
    if (lane == 0) gpart[(size_t)w * 8 + g] = make_float2(s_, s2_);
  }
}

// One qkv+attention pass for heads PH*2, PH*2+1.  PH literal (rule #20).
#define QKV_ATTN_PASS(PH)                                                      \
  {                                                                            \
    {                                                                          \
      int sec = wave >> 2;              /* 0=q 1=k 2=v */                      \
      int tloc = wave & 3;                                                     \
      int cols16 = sec * 192 + (PH) * 64 + tloc * 16;                          \
      int lh = tloc >> 1;                                                      \
      int d = ((tloc & 1) << 4) + p;                                           \
      f32x4 acc0 = zz, acc1 = zz, acc2 = zz, acc3 = zz;                        \
      _Pragma("unroll")                                                        \
      for (int ks = 0; ks < 6; ++ks) {                                         \
        int k0 = ks * 32 + q8 * 8;                                             \
        bf16x8 bfr = *(const bf16x8*)(qkvT + (size_t)(cols16 + p) * DIM + k0); \
        acc0 = MFMA16(*(const bf16x8*)&tile[0 * 16 + p][k0], bfr, acc0);       \
        acc1 = MFMA16(*(const bf16x8*)&tile[1 * 16 + p][k0], bfr, acc1);       \
        acc2 = MFMA16(*(const bf16x8*)&tile[2 * 16 + p][k0], bfr, acc2);       \
        acc3 = MFMA16(*(const bf16x8*)&tile[3 * 16 + p][k0], bfr, acc3);       \
      }                                                                        \
      float bias = qkv_b[cols16 + p];                                          \
      if (sec == 0) {                                                          \
        int base = q8 * 4;                                                     \
        _Pragma("unroll")                                                      \
        for (int r = 0; r < 4; ++r) {                                          \
          qkP[lh][(0 * 16 + base + r) * 40 + d] = f2b((acc0[r] + bias) * SCALE); \
          qkP[lh][(1 * 16 + base + r) * 40 + d] = f2b((acc1[r] + bias) * SCALE); \
          qkP[lh][(2 * 16 + base + r) * 40 + d] = f2b((acc2[r] + bias) * SCALE); \
          qkP[lh][(3 * 16 + base + r) * 40 + d] = f2b((acc3[r] + bias) * SCALE); \
        }                                                                      \
      } else if (sec == 1) {                                                   \
        int base = q8 * 4;                                                     \
        _Pragma("unroll")                                                      \
        for (int r = 0; r < 4; ++r) {                                          \
          qkP[lh][2560 + (0 * 16 + base + r) * 40 + d] = f2b(acc0[r] + bias);  \
          qkP[lh][2560 + (1 * 16 + base + r) * 40 + d] = f2b(acc1[r] + bias);  \
          qkP[lh][2560 + (2 * 16 + base + r) * 40 + d] = f2b(acc2[r] + bias);  \
          qkP[lh][2560 + (3 * 16 + base + r) * 40 + d] = f2b(acc3[r] + bias);  \
        }                                                                      \
      } else {                                                                 \
        u16x4 v0, v1, v2, v3;                                                  \
        _Pragma("unroll")                                                      \
        for (int r = 0; r < 4; ++r) {                                          \
          v0[r] = f2b(acc0[r] + bias);                                         \
          v1[r] = f2b(acc1[r] + bias);                                         \
          v2[r] = f2b(acc2[r] + bias);                                         \
          v3[r] = f2b(acc3[r] + bias);                                         \
        }                                                                      \
        int base = d * 72 + q8 * 4;                                            \
        *(u16x4*)&vT[lh][base + 0]  = v0;                                      \
        *(u16x4*)&vT[lh][base + 16] = v1;                                      \
        *(u16x4*)&vT[lh][base + 32] = v2;                                      \
        *(u16x4*)&vT[lh][base + 48] = v3;                                      \
      }                                                                        \
    }                                                                          \
    __syncthreads(); /* B2 */                                                  \
    {                                                                          \
      int lh = (wave >> 2) & 1, quad = wave & 3;                               \
      int rb_ = quad << 4;                                                     \
      int k0 = q8 * 8;                                                         \
      f32x4 s0 = zz, s1 = zz, s2 = zz, s3 = zz;                                \
      if (wave < 8) {                                                          \
        const ushort_t* qh = &qkP[lh][0];                                      \
        const ushort_t* kh = &qkP[lh][2560];                                   \
        bf16x8 aq = *(const bf16x8*)&qh[(rb_ + p) * 40 + k0];                  \
        bf16x8 bk0 = *(const bf16x8*)&kh[(0 + p) * 40 + k0];                   \
        bf16x8 bk1 = *(const bf16x8*)&kh[(16 + p) * 40 + k0];                  \
        bf16x8 bk2 = *(const bf16x8*)&kh[(32 + p) * 40 + k0];                  \
        bf16x8 bk3 = *(const bf16x8*)&kh[(48 + p) * 40 + k0];                  \
        s0 = MFMA16(aq, bk0, zz);                                              \
        s1 = MFMA16(aq, bk1, zz);                                              \
        s2 = MFMA16(aq, bk2, zz);                                              \
        s3 = MFMA16(aq, bk3, zz);                                              \
      }                                                                        \
      __syncthreads(); /* B3: q/k reads done before P overwrite */             \
      if (wave < 8) {                                                          \
        ushort_t* Ph = &qkP[lh][0];                                            \
        _Pragma("unroll")                                                      \
        for (int r = 0; r < 4; ++r) {                                          \
          float m = fmaxf(fmaxf(s0[r], s1[r]), fmaxf(s2[r], s3[r]));           \
          for (int msk = 1; msk < 16; msk <<= 1) m = fmaxf(m, __shfl_xor(m, msk)); \
          float e0 = __expf(s0[r] - m);                                        \
          float e1 = __expf(s1[r] - m);                                        \
          float e2 = __expf(s2[r] - m);                                        \
          float e3 = __expf(s3[r] - m);                                        \
          float sum = e0 + e1 + e2 + e3;                                       \
          for (int msk = 1; msk < 16; msk <<= 1) sum += __shfl_xor(sum, msk);  \
          float inv = 1.0f / sum;                                              \
          int row = rb_ + q8 * 4 + r;                                          \
          Ph[row * 72 + 0 + p]  = f2b(e0 * inv);                               \
          Ph[row * 72 + 16 + p] = f2b(e1 * inv);                               \
          Ph[row * 72 + 32 + p] = f2b(e2 * inv);                               \
          Ph[row * 72 + 48 + p] = f2b(e3 * inv);                               \
        }                                                                      \
        f32x4 o0 = zz, o1 = zz;                                                \
        _Pragma("unroll")                                                      \
        for (int ks = 0; ks < 2; ++ks) {                                       \
          int kk = ks * 32 + k0;                                               \
          bf16x8 bv0 = *(const bf16x8*)&vT[lh][(0 + p) * 72 + kk];             \
          bf16x8 bv1 = *(const bf16x8*)&vT[lh][(16 + p) * 72 + kk];            \
          bf16x8 ap = *(const bf16x8*)&Ph[(rb_ + p) * 72 + kk];                \
          o0 = MFMA16(ap, bv0, o0);                                            \
          o1 = MFMA16(ap, bv1, o1);                                            \
        }                                                                      \
        size_t ob = (size_t)w * 12288 + (size_t)(rb_ + q8 * 4) * 192 +         \
                    ((PH) * 2 + lh) * 32 + p;                                  \
        _Pragma("unroll")                                                      \
        for (int r = 0; r < 4; ++r) {                                          \
          obuf[ob + (size_t)r * 192]      = f2b(o0[r]);                        \
          obuf[ob + (size_t)r * 192 + 16] = f2b(o1[r]);                        \
        }                                                                      \
      }                                                                        \
    }                                                                          \
  }

// ---------------- K_a: qkv + attention -------------------------------------
__global__ __launch_bounds__(768, 3) void attn_kernel(
    const ushort_t* __restrict__ buf_xn,
    const ushort_t* __restrict__ qkvTb_, const float* __restrict__ qkvbb_,
    ushort_t* __restrict__ obuf) {
  int w = blockIdx.x;
  int tid = threadIdx.x;
  int wave = tid >> 6, lane = tid & 63;
  int p = lane & 15, q8 = lane >> 4;

  const ushort_t* qkvT = qkvTb_ + (size_t)(w >> 10) * 110592;   // 576*192
  const float* qkv_b = qkvbb_ + (w >> 10) * 576;

  __shared__ __align__(16) ushort_t tile[64][200];  // x win (token-major)
  __shared__ __align__(16) ushort_t qkP[2][5120];   // q|k -> P, per head
  __shared__ __align__(16) ushort_t vT[2][2304];    // v^T [32][72]

  const ushort_t* bw = buf_xn + (size_t)w * 12288;
#pragma unroll
  for (int it = 0; it < 2; ++it) {
    int u = it * 768 + tid;
    int token = u / 24, cv = u - token * 24;
    *(u16x8*)&tile[token][cv * 8] = *(const u16x8*)&bw[u * 8];
  }
  __syncthreads();   // B1

  const f32x4 zz = {0.f, 0.f, 0.f, 0.f};

  QKV_ATTN_PASS(0)
  __syncthreads();   // B4
  QKV_ATTN_PASS(1)
  __syncthreads();   // B4
  QKV_ATTN_PASS(2)
}

// ---------------- K_b2: proj + residual from windowed bf16 x_win -----------
// O in obuf, x_win in xwin (both token-major windowed) -> x_mid into obuf.
__global__ __launch_bounds__(256) void proj_kernel2(
    ushort_t* __restrict__ obuf, const ushort_t* __restrict__ xwin,
    const ushort_t* __restrict__ projT, const float* __restrict__ proj_b,
    float2* __restrict__ gpart) {
  int w = blockIdx.x;
  int tid = threadIdx.x;
  int wave = tid >> 6, lane = tid & 63;
  int p = lane & 15, q8 = lane >> 4;

  __shared__ __align__(16) ushort_t otile[64][200];  // O -> proj-out -> red

  ushort_t* bw = obuf + (size_t)w * 12288;
  const ushort_t* xw = xwin + (size_t)w * 12288;

#pragma unroll
  for (int it = 0; it < 6; ++it) {
    int idx = (it * 256 + tid) * 8;
    int t = idx / 192, c = idx - t * 192;
    *(u16x8*)&otile[t][c] = *(const u16x8*)&bw[idx];
  }
  __syncthreads();

  const f32x4 zz = {0.f, 0.f, 0.f, 0.f};
  f32x4 prr[3][4];
#pragma unroll
  for (int rd = 0; rd < 3; ++rd) {
    int col = rd * 64 + wave * 16 + p;
#pragma unroll
    for (int mt = 0; mt < 4; ++mt) prr[rd][mt] = zz;
#pragma unroll
    for (int ks = 0; ks < 6; ++ks) {
      int k0 = ks * 32 + q8 * 8;
      bf16x8 bfr = *(const bf16x8*)(projT + (size_t)col * DIM + k0);
      prr[rd][0] = MFMA16(*(const bf16x8*)&otile[0 * 16 + p][k0], bfr, prr[rd][0]);
      prr[rd][1] = MFMA16(*(const bf16x8*)&otile[1 * 16 + p][k0], bfr, prr[rd][1]);
      prr[rd][2] = MFMA16(*(const bf16x8*)&otile[2 * 16 + p][k0], bfr, prr[rd][2]);
      prr[rd][3] = MFMA16(*(const bf16x8*)&otile[3 * 16 + p][k0], bfr, prr[rd][3]);
    }
  }
  __syncthreads();

#pragma unroll
  for (int rd = 0; rd < 3; ++rd) {
    int col = rd * 64 + wave * 16 + p;
    float bias = proj_b[col];
#pragma unroll
    for (int mt = 0; mt < 4; ++mt)
#pragma unroll
      for (int r = 0; r < 4; ++r)
        otile[mt * 16 + q8 * 4 + r][col] = f2b(prr[rd][mt][r] + bias);
  }
  __syncthreads();

  // residual = proj-out + x_win (both token-major) -> x_mid + GN2 partials
  float sacc[6], s2acc[6];
#pragma unroll
  for (int it = 0; it < 6; ++it) {
    int u = it * 256 + tid;
    int token = u / 24, cv = u - token * 24;
    u16x8 ov = *(const u16x8*)&otile[token][cv * 8];
    u16x8 xv = *(const u16x8*)&xw[u * 8];
    u16x8 rv;
    float s_ = 0.f, s2_ = 0.f;
#pragma unroll
    for (int t = 0; t < 8; ++t) {
      rv[t] = f2b(b2f(ov[t]) + b2f(xv[t]));
      float fb = b2f(rv[t]);
      s_ += fb; s2_ += fb * fb;
    }
    *(u16x8*)&bw[u * 8] = rv;
    sacc[it] = s_; s2acc[it] = s2_;
  }
  __syncthreads();   // otile reads done; red aliases otile

  float2* red = (float2*)&otile[0][0];
#pragma unroll
  for (int it = 0; it < 6; ++it)
    red[it * 256 + tid] = make_float2(sacc[it], s2acc[it]);
  __syncthreads();

  for (int g = wave; g < 8; g += 4) {
    float s_ = 0.f, s2_ = 0.f;
#pragma unroll
    for (int j = 0; j < 3; ++j) {
      float2 t_ = red[lane * 24 + g * 3 + j];
      s_ += t_.x; s2_ += t_.y;
    }
    for (int m = 1; m < 64; m <<= 1) { s_ += __shfl_xor(s_, m); s2_ += __shfl_xor(s2_, m); }
    if (lane == 0) gpart[(size_t)w * 8 + g] = make_float2(s_, s2_);
  }
}

// ---------------- K_b: proj + residual (fp32 x fallback, r15 path) ---------
__global__ __launch_bounds__(256) void proj_kernel(
    ushort_t* __restrict__ buf,
    const ushort_t* __restrict__ projT, const float* __restrict__ proj_b,
    const float* __restrict__ x, float2* __restrict__ gpart) {
  int w = blockIdx.x;
  int b = w >> 10, wh = (w >> 5) & 31, ww = w & 31;
  int tid = threadIdx.x;
  int wave = tid >> 6, lane = tid & 63;
  int p = lane & 15, q8 = lane >> 4;
  int C3 = lane >> 3, I = lane & 7;

  __shared__ __align__(16) ushort_t otile[64][200];

  ushort_t* bw = buf + (size_t)w * 12288;

#pragma unroll
  for (int it = 0; it < 6; ++it) {
    int idx = (it * 256 + tid) * 8;
    int t = idx / 192, c = idx - t * 192;
    *(u16x8*)&otile[t][c] = *(const u16x8*)&bw[idx];
  }
  __syncthreads();

  const f32x4 zz = {0.f, 0.f, 0.f, 0.f};
  f32x4 prr[3][4];
#pragma unroll
  for (int rd = 0; rd < 3; ++rd) {
    int col = rd * 64 + wave * 16 + p;
#pragma unroll
    for (int mt = 0; mt < 4; ++mt) prr[rd][mt] = zz;
#pragma unroll
    for (int ks = 0; ks < 6; ++ks) {
      int k0 = ks * 32 + q8 * 8;
      bf16x8 bfr = *(const bf16x8*)(projT + (size_t)col * DIM + k0);
      prr[rd][0] = MFMA16(*(const bf16x8*)&otile[0 * 16 + p][k0], bfr, prr[rd][0]);
      prr[rd][1] = MFMA16(*(const bf16x8*)&otile[1 * 16 + p][k0], bfr, prr[rd][1]);
      prr[rd][2] = MFMA16(*(const bf16x8*)&otile[2 * 16 + p][k0], bfr, prr[rd][2]);
      prr[rd][3] = MFMA16(*(const bf16x8*)&otile[3 * 16 + p][k0], bfr, prr[rd][3]);
    }
  }
  __syncthreads();

#pragma unroll
  for (int rd = 0; rd < 3; ++rd) {
    int col = rd * 64 + wave * 16 + p;
    float bias = proj_b[col];
#pragma unroll
    for (int mt = 0; mt < 4; ++mt)
#pragma unroll
      for (int r = 0; r < 4; ++r)
        otile[mt * 16 + q8 * 4 + r][col] = f2b(prr[rd][mt][r] + bias);
  }
  __syncthreads();

  int px0 = (ww << 3) + 4;
  int px1 = (px0 + 4) & 255;

#pragma unroll
  for (int it = 0; it < 6; ++it) {
    int u = it * 256 + tid;
    int c = u >> 3, i = u & 7;
    int cbase = it * 32 + wave * 8;
    u16x8 rr = *(const u16x8*)&otile[I * 8 + C3][cbase];
    ushort_t V[8];
#pragma unroll
    for (int j = 0; j < 8; ++j) V[j] = rr[j];
    xpose8(V, C3);
    int py = ((wh << 3) + i + 4) & 255;
    const float* src = x + (((size_t)(b * DIM + c)) << 16) + (py << 8);
    float4 ra = *(const float4*)(src + px0);
    V[0] = f2b(ra.x + b2f(V[0]));
    V[1] = f2b(ra.y + b2f(V[1]));
    V[2] = f2b(ra.z + b2f(V[2]));
    V[3] = f2b(ra.w + b2f(V[3]));
    float4 rb2 = *(const float4*)(src + px1);
    V[4] = f2b(rb2.x + b2f(V[4]));
    V[5] = f2b(rb2.y + b2f(V[5]));
    V[6] = f2b(rb2.z + b2f(V[6]));
    V[7] = f2b(rb2.w + b2f(V[7]));
    xpose8(V, C3);
    u16x8 wv;
#pragma unroll
    for (int j = 0; j < 8; ++j) wv[j] = V[j];
    *(u16x8*)&otile[I * 8 + C3][cbase] = wv;
  }
  __syncthreads();

  float sacc[6], s2acc[6];
#pragma unroll
  for (int it = 0; it < 6; ++it) {
    int u = it * 256 + tid;
    int token = u / 24, cv = u - token * 24;
    u16x8 v = *(const u16x8*)&otile[token][cv * 8];
    *(u16x8*)&bw[u * 8] = v;
    float s_ = 0.f, s2_ = 0.f;
#pragma unroll
    for (int t = 0; t < 8; ++t) { float f = b2f(v[t]); s_ += f; s2_ += f * f; }
    sacc[it] = s_; s2acc[it] = s2_;
  }
  __syncthreads();

  float2* red = (float2*)&otile[0][0];
#pragma unroll
  for (int it = 0; it < 6; ++it)
    red[it * 256 + tid] = make_float2(sacc[it], s2acc[it]);
  __syncthreads();

  for (int g = wave; g < 8; g += 4) {
    float s_ = 0.f, s2_ = 0.f;
#pragma unroll
    for (int j = 0; j < 3; ++j) {
      float2 t_ = red[lane * 24 + g * 3 + j];
      s_ += t_.x; s2_ += t_.y;
    }
    for (int m = 1; m < 64; m <<= 1) { s_ += __shfl_xor(s_, m); s2_ += __shfl_xor(s2_, m); }
    if (lane == 0) gpart[(size_t)w * 8 + g] = make_float2(s_, s2_);
  }
}

// ---------------- fused MLP + residual2 (GN2 folded; resid from LDS) -------
__global__ __launch_bounds__(256, 4) void mlp_kernel(
    const ushort_t* __restrict__ x_mid,
    const ushort_t* __restrict__ w1b, const float* __restrict__ b1b,
    const ushort_t* __restrict__ w2T, const float* __restrict__ b2,
    float* __restrict__ out) {
  int bid = blockIdx.x;
  int b = bid >> 10, y = (bid >> 2) & 255, xq = bid & 3;
  int x0 = xq * 64;
  int tid = threadIdx.x;
  int wave = tid >> 6, lane = tid & 63;
  int p = lane & 15, q = lane >> 4;

  __shared__ ushort_t xn[64][200];   // xm tile, later mlp-out staging
  __shared__ ushort_t hb[64][72];    // hidden chunk [token][hid]

  const ushort_t* w1T = w1b + (size_t)b * 147456;   // 768*192
  const float* b1 = b1b + b * 768;

  int yp = (y + 252) & 255;          // (y - 4) mod 256
  int whp = yp >> 3, ip = yp & 7;
  size_t winrow = ((size_t)b * 1024 + (size_t)whp * 32) * 12288;

  for (int u = tid; u < 1536; u += 256) {
    int tx = u / 24, ch = u - tx * 24;
    int c8 = ch * 8;
    int xp = (x0 + tx + 252) & 255;  // (x - 4) mod 256
    *(u16x8*)&xn[tx][c8] =
        *(const u16x8*)(x_mid + winrow + (size_t)(xp >> 3) * 12288 +
                        (size_t)(ip * 8 + (xp & 7)) * 192 + c8);
  }
  __syncthreads();

  const f32x4 zz = {0.f, 0.f, 0.f, 0.f};
  f32x4 accO[4][3];
#pragma unroll
  for (int mt = 0; mt < 4; ++mt)
#pragma unroll
    for (int nt = 0; nt < 3; ++nt) accO[mt][nt] = zz;

  for (int ch = 0; ch < 12; ++ch) {
    int hcol16 = ch * 64 + wave * 16;
    f32x4 a1[4];
#pragma unroll
    for (int mt = 0; mt < 4; ++mt) a1[mt] = zz;
#pragma unroll
    for (int ks = 0; ks < 6; ++ks) {
      int k0 = ks * 32 + q * 8;
      bf16x8 wfr = *(const bf16x8*)(w1T + (size_t)(hcol16 + p) * DIM + k0);
#pragma unroll
      for (int mt = 0; mt < 4; ++mt) {
        bf16x8 afr = *(const bf16x8*)&xn[mt * 16 + p][k0];
        a1[mt] = MFMA16(wfr, afr, a1[mt]);   // swapped: weights=rows, tokens=cols
      }
    }
    float4 bb = *(const float4*)&b1[hcol16 + q * 4];
    if (ch) __syncthreads();
#pragma unroll
    for (int mt = 0; mt < 4; ++mt) {
      u16x4 hv;
#pragma unroll
      for (int r = 0; r < 4; ++r) {
        float vv = a1[mt][r] + ((const float*)&bb)[r];
        float g = vv / (1.0f + __expf(-1.702f * vv));   // sigmoid-GELU
        hv[r] = f2b(g);
      }
      *(u16x4*)&hb[mt * 16 + p][wave * 16 + q * 4] = hv;
    }
    __syncthreads();
#pragma unroll
    for (int ks = 0; ks < 2; ++ks) {
      int k0 = ks * 32 + q * 8;
      bf16x8 w20 = *(const bf16x8*)(w2T + (size_t)(wave * 48 + 0 * 16 + p) * HID + ch * 64 + k0);
      bf16x8 w21 = *(const bf16x8*)(w2T + (size_t)(wave * 48 + 1 * 16 + p) * HID + ch * 64 + k0);
      bf16x8 w22 = *(const bf16x8*)(w2T + (size_t)(wave * 48 + 2 * 16 + p) * HID + ch * 64 + k0);
#pragma unroll
      for (int mt = 0; mt < 4; ++mt) {
        bf16x8 afr = *(const bf16x8*)&hb[mt * 16 + p][k0];
        accO[mt][0] = MFMA16(afr, w20, accO[mt][0]);
        accO[mt][1] = MFMA16(afr, w21, accO[mt][1]);
        accO[mt][2] = MFMA16(afr, w22, accO[mt][2]);
      }
    }
  }
  // xn still holds raw xm: grab this thread's residual values before overwrite
  u16x8 raws[6];
#pragma unroll
  for (int cg = 0; cg < 6; ++cg) {
    int chunk = (tid >> 6) + cg * 4;
    raws[cg] = *(const u16x8*)&xn[tid & 63][chunk * 8];
  }
  __syncthreads();   // all xn/hb reads done before staging overwrites xn

#pragma unroll
  for (int mt = 0; mt < 4; ++mt)
#pragma unroll
    for (int nt = 0; nt < 3; ++nt) {
      int col = wave * 48 + nt * 16 + p;
      float bias = b2[col];
#pragma unroll
      for (int r = 0; r < 4; ++r)
        xn[mt * 16 + q * 4 + r][col] = f2b(accO[mt][nt][r] + bias);
    }
  __syncthreads();

#pragma unroll
  for (int cg = 0; cg < 6; ++cg) {
    int chunk = (tid >> 6) + cg * 4;          // 0..23
    int txx = tid & 63;
    int c8 = chunk * 8;
    u16x8 raw = raws[cg];
    u16x8 mo = *(const u16x8*)&xn[txx][c8];
#pragma unroll
    for (int t = 0; t < 8; ++t) {
      out[(((size_t)(b * DIM + c8 + t)) << 16) + (y << 8) + x0 + txx] =
          b2f(raw[t]) + b2f(mo[t]);
    }
  }
}

// ---------------- host launcher --------------------------------------------
extern "C" void kernel_launch(void* const* d_in, const int* in_sizes, int n_in,
                              void* d_out, int out_size, void* d_ws, size_t ws_size,
                              hipStream_t stream) {
  const float* x      = (const float*)d_in[0];
  const float* qkv_w  = (const float*)d_in[1];
  const float* qkv_b  = (const float*)d_in[2];
  const float* proj_w = (const float*)d_in[3];
  const float* proj_b = (const float*)d_in[4];
  const float* n1w    = (const float*)d_in[5];
  const float* n1b    = (const float*)d_in[6];
  const float* n2w    = (const float*)d_in[7];
  const float* n2b    = (const float*)d_in[8];
  const float* mlp_w1 = (const float*)d_in[9];
  const float* mlp_b1 = (const float*)d_in[10];
  const float* mlp_w2 = (const float*)d_in[11];
  const float* mlp_b2 = (const float*)d_in[12];
  float* out = (float*)d_out;

  char* ws = (char*)d_ws;
  const size_t XMID_B = (size_t)NWIN * 64 * DIM * 2;          // 100663296
  const size_t WP_B   = 2717184;
  ushort_t* buf   = (ushort_t*)ws;     // x_win (-> O -> x_mid in fallback)
  char* wp = ws + XMID_B;
  ushort_t* projT = (ushort_t*)(wp);                 // 73728
  ushort_t* w2T   = (ushort_t*)(wp + 73728);         // 294912
  ushort_t* qkvTb = (ushort_t*)(wp + 368640);        // 884736
  float*    qkvbb = (float*)   (wp + 1253376);       // 9216
  ushort_t* w1b   = (ushort_t*)(wp + 1262592);       // 1179648
  float*    b1b   = (float*)   (wp + 2442240);       // 12288
  float* stats1   = (float*)   (wp + 2454528);       // 256
  float* stats2   = (float*)   (wp + 2454784);       // 256
  float2* gpart   = (float2*)  (wp + 2455040);       // 262144
  ushort_t* buf2  = (ushort_t*)(wp + WP_B);          // second 100 MB (if room)
  bool two = ws_size >= XMID_B + WP_B + XMID_B;

  transpose_w<<<(192 * 192 + 255) / 256, 256, 0, stream>>>(proj_w, projT, 192, 192);
  transpose_w<<<(192 * 768 + 255) / 256, 256, 0, stream>>>(mlp_w2, w2T, 768, 192);

  win_x<<<NWIN, 256, 0, stream>>>(x, buf, gpart);

  gn2_reduce<<<32, 64, 0, stream>>>(gpart, stats1);

  fold_w<<<4 * 36, 256, 0, stream>>>(qkv_w, qkv_b, stats1, n1w, n1b,
                                     qkvTb, qkvbb, 576);

  if (two) {
    attn_kernel<<<NWIN, 768, 0, stream>>>(buf, qkvTb, qkvbb, buf2);
    proj_kernel2<<<NWIN, 256, 0, stream>>>(buf2, buf, projT, proj_b, gpart);
  } else {
    attn_kernel<<<NWIN, 768, 0, stream>>>(buf, qkvTb, qkvbb, buf);
    proj_kernel<<<NWIN, 256, 0, stream>>>(buf, projT, proj_b, x, gpart);
  }

  gn2_reduce<<<32, 64, 0, stream>>>(gpart, stats2);

  fold_w<<<4 * 48, 256, 0, stream>>>(mlp_w1, mlp_b1, stats2, n2w, n2b,
                                     w1b, b1b, 768);

  mlp_kernel<<<NWIN, 256, 0, stream>>>(two ? buf2 : buf, w1b, b1b, w2T, mlp_b2, out);
}